// Round 21
// baseline (232.740 us; speedup 1.0000x reference)
//
#include <hip/hip_runtime.h>
#include <hip/hip_bf16.h>

#define NN 50000
#define NE 800000
#define DD 128
#define BN_EPS 1e-5f
#define SCAN_G 98     // 98*512 = 50176 >= NN
#define NB 125        // edge chunks (blocks) in lds_count
#define BT 640        // lds_count block threads (10 waves)
#define CHUNK 6400    // NB*CHUNK = NE; 6400 = 10*640 (exact)
#define NWRD 25000    // packed u16x2 counters: 2 dst per u32 word

typedef unsigned short ushort_t;
typedef unsigned int uint_t;
typedef __attribute__((ext_vector_type(8))) short short8v;   // 8 x bf16 (4 VGPR)
typedef __attribute__((ext_vector_type(4))) float f32x4;

__device__ __forceinline__ float b2f(ushort_t u) {
    union { uint_t i; float f; } v; v.i = ((uint_t)u) << 16; return v.f;
}
__device__ __forceinline__ ushort_t f2b(float f) {
    uint_t u = __float_as_uint(f);
    u += 0x7FFFu + ((u >> 16) & 1u);   // RNE
    return (ushort_t)(u >> 16);
}
__device__ __forceinline__ void atomAdd(float* p, float v) { unsafeAtomicAdd(p, v); }

// ---------- pass A: per-block LDS histogram + local rank + feat->bf16 ----------
// h[w] packs counts for dst=2w (lo16) and dst=2w+1 (hi16). Per-block count
// <= 6400 so no overflow / no cross-half carry. LDS atomic returns local rank.
__global__ __launch_bounds__(BT) void lds_count(const int* __restrict__ dst,
                                                int* __restrict__ cnt_block,
                                                ushort_t* __restrict__ rank16,
                                                const float* __restrict__ feat,
                                                ushort_t* __restrict__ feat_bf,
                                                float4* __restrict__ gz,
                                                int* __restrict__ part) {
    __shared__ uint_t h[NWRD];     // 100 KB
    int b = blockIdx.x, t = threadIdx.x;
    for (int i = t; i < NWRD; i += BT) h[i] = 0u;
    // feat conversion, grid-strided: 1.6M float4 / 80000 threads = 20 exact
    {
        const float4* fp = reinterpret_cast<const float4*>(feat);
        ushort4* op = reinterpret_cast<ushort4*>(feat_bf);
        for (int i = b * BT + t; i < 1600000; i += NB * BT) {
            float4 v = fp[i];
            ushort4 o = { f2b(v.x), f2b(v.y), f2b(v.z), f2b(v.w) };
            op[i] = o;
        }
    }
    if (b == 0) {
        float4 z = make_float4(0.f, 0.f, 0.f, 0.f);
        for (int i = t; i < 2048; i += BT) gz[i] = z;   // gsums+gsq = 32 KB
        if (t < 128) part[t] = 0;                       // part (98 ints)
    }
    __syncthreads();
    int e0 = b * CHUNK;
    #pragma unroll
    for (int k = 0; k < 10; ++k) {         // 10*640 = 6400 exact
        int e = e0 + k * BT + t;
        int d = dst[e];
        int sh = (d & 1) << 4;
        uint_t old = atomicAdd(&h[d >> 1], 1u << sh);
        rank16[e] = (ushort_t)((old >> sh) & 0xFFFFu);
    }
    __syncthreads();
    for (int i = t; i < NWRD; i += BT) cnt_block[b * NWRD + i] = (int)h[i];
}

// ---------- pass B: per-word exclusive scan over blocks (in place) ----------
// Also emits deg, norm, and per-512-node partial sums (replaces scan_part).
__global__ __launch_bounds__(256) void col_scan(int* __restrict__ cnt_block,
                                                int2* __restrict__ deg2,
                                                float* __restrict__ norm,
                                                int* __restrict__ part) {
    int w = blockIdx.x * 256 + threadIdx.x;   // 98*256 = 25088 >= NWRD
    if (w >= NWRD) return;
    uint_t run = 0;
    #pragma unroll 5
    for (int b = 0; b < NB; ++b) {
        uint_t v = (uint_t)cnt_block[b * NWRD + w];
        cnt_block[b * NWRD + w] = (int)run;
        run += v;
    }
    int d0 = (int)(run & 0xFFFFu), d1 = (int)(run >> 16);
    deg2[w] = make_int2(d0, d1);
    norm[2 * w]     = rsqrtf((float)max(d0, 1));   // 2w   <= 49998 < NN
    norm[2 * w + 1] = rsqrtf((float)max(d1, 1));   // 2w+1 <= 49999 < NN
    atomicAdd(&part[w >> 8], d0 + d1);             // 256 words = 512 nodes / slot
}

// off-scan (blocks < SCAN_G): block-local exclusive scan + in-block base.
// blocks >= SCAN_G: build WcT (128x384 bf16).
__global__ __launch_bounds__(512) void scan_final(const int* __restrict__ deg,
                                                  const int* __restrict__ part,
                                                  int* __restrict__ off,
                                                  const float* __restrict__ W1,
                                                  const float* __restrict__ W2,
                                                  const float* __restrict__ W3,
                                                  ushort_t* __restrict__ wcT) {
    if (blockIdx.x >= SCAN_G) {
        int i = (blockIdx.x - SCAN_G) * 512 + threadIdx.x;   // 96*512 = 49152
        int d = i / 384, k = i % 384;
        float v;
        if (k < 128)      v = W1[k * DD + d] - W3[k * DD + d];
        else if (k < 256) v = -W2[(k - 128) * DD + d];
        else              v = 2.0f * W3[(k - 256) * DD + d];
        wcT[i] = f2b(v);
        return;
    }
    __shared__ int wsum[8];
    __shared__ int sbase;
    int t = threadIdx.x;
    int lane = t & 63, wv = t >> 6;

    int p = (t < blockIdx.x && t < SCAN_G) ? part[t] : 0;
    #pragma unroll
    for (int s = 1; s < 64; s <<= 1) p += __shfl_xor(p, s);
    if (lane == 0) wsum[wv] = p;
    __syncthreads();
    if (t == 0) {
        int b = 0;
        #pragma unroll
        for (int k = 0; k < 8; ++k) b += wsum[k];
        sbase = b;
    }
    __syncthreads();

    int i = blockIdx.x * 512 + t;
    int v = (i < NN) ? deg[i] : 0;
    int incl = v;
    #pragma unroll
    for (int s = 1; s < 64; s <<= 1) {
        int u = __shfl_up(incl, s);
        if (lane >= s) incl += u;
    }
    __syncthreads();
    if (lane == 63) wsum[wv] = incl;
    __syncthreads();
    int woff = 0;
    for (int k = 0; k < wv; ++k) woff += wsum[k];
    int excl = sbase + woff + incl - v;
    if (i < NN) off[i] = excl;
    if (blockIdx.x == 0 && t == 0) off[NN] = NE;
}

// ---------- pass C: atomic-free CSR fill ----------
// p = off[dst] + prefix[block][dst] + rank16[e]
__global__ void fill2(const int* __restrict__ src, const int* __restrict__ dst,
                      const ushort_t* __restrict__ rank16,
                      const int* __restrict__ cnt_block,   // now prefix
                      const int* __restrict__ off,
                      const float* __restrict__ norm, int2* __restrict__ csr) {
    int e = blockIdx.x * 256 + threadIdx.x;
    if (e >= NE) return;
    int b = e / CHUNK;
    int s = src[e], d = dst[e];
    int sh = (d & 1) << 4;
    uint_t pref = ((uint_t)cnt_block[b * NWRD + (d >> 1)] >> sh) & 0xFFFFu;
    int p = off[d] + (int)pref + (int)rank16[e];
    csr[p] = make_int2(s, __float_as_int(norm[s]));
}

// ---------- message passing (bf16 in, bf16 out) ----------
// QUARTER-WAVE (16 lanes) per NODE; lane covers 8 cols (uint4 = 16B).
__global__ __launch_bounds__(256) void gather_bf(const ushort_t* __restrict__ x,
                                                 const float* __restrict__ norm,
                                                 const int* __restrict__ off,
                                                 const int2* __restrict__ csr,
                                                 ushort_t* __restrict__ out) {
    int g = (blockIdx.x << 4) | (threadIdx.x >> 4);   // node id; 3125*16 = 50000
    int l4 = threadIdx.x & 15;
    int jb = off[g], je = off[g + 1];
    const uint4* xp = reinterpret_cast<const uint4*>(x);   // row = 16 x uint4
    float a0 = 0.f, a1 = 0.f, a2 = 0.f, a3 = 0.f;
    float a4 = 0.f, a5 = 0.f, a6 = 0.f, a7 = 0.f;

#define ACC(cc, vv)                                                  \
    {                                                                \
        float n_ = __int_as_float(cc.y);                             \
        a0 = fmaf(n_, b2f((ushort_t)(vv.x)), a0);                    \
        a1 = fmaf(n_, b2f((ushort_t)(vv.x >> 16)), a1);              \
        a2 = fmaf(n_, b2f((ushort_t)(vv.y)), a2);                    \
        a3 = fmaf(n_, b2f((ushort_t)(vv.y >> 16)), a3);              \
        a4 = fmaf(n_, b2f((ushort_t)(vv.z)), a4);                    \
        a5 = fmaf(n_, b2f((ushort_t)(vv.z >> 16)), a5);              \
        a6 = fmaf(n_, b2f((ushort_t)(vv.w)), a6);                    \
        a7 = fmaf(n_, b2f((ushort_t)(vv.w >> 16)), a7);              \
    }

    int j = jb;
    for (; j + 4 <= je; j += 4) {
        int2 c0 = csr[j + 0];
        int2 c1 = csr[j + 1];
        int2 c2 = csr[j + 2];
        int2 c3 = csr[j + 3];
        uint4 v0 = xp[(size_t)c0.x * 16 + l4];
        uint4 v1 = xp[(size_t)c1.x * 16 + l4];
        uint4 v2 = xp[(size_t)c2.x * 16 + l4];
        uint4 v3 = xp[(size_t)c3.x * 16 + l4];
        ACC(c0, v0); ACC(c1, v1); ACC(c2, v2); ACC(c3, v3);
    }
    for (; j < je; ++j) {
        int2 c = csr[j];
        uint4 v = xp[(size_t)c.x * 16 + l4];
        ACC(c, v);
    }
#undef ACC

    float nd = norm[g];
    uint4 o;
    o.x = (uint_t)f2b(nd * a0) | ((uint_t)f2b(nd * a1) << 16);
    o.y = (uint_t)f2b(nd * a2) | ((uint_t)f2b(nd * a3) << 16);
    o.z = (uint_t)f2b(nd * a4) | ((uint_t)f2b(nd * a5) << 16);
    o.w = (uint_t)f2b(nd * a6) | ((uint_t)f2b(nd * a7) << 16);
    reinterpret_cast<uint4*>(out)[(size_t)g * 16 + l4] = o;
}

// ---------- MFMA GEMM + BN partials ----------
__global__ __launch_bounds__(256) void gemm_bn(
    const ushort_t* __restrict__ feat_bf, const ushort_t* __restrict__ ax_bf,
    const ushort_t* __restrict__ ax2_bf, const ushort_t* __restrict__ wcT,
    const float* __restrict__ bias, const float* __restrict__ snorm,
    ushort_t* __restrict__ t_out, float* __restrict__ gsums, float* __restrict__ gsq)
{
    __shared__ ushort_t As[128 * 128];   // 32 KB, XOR-swizzled
    __shared__ ushort_t Bs[128 * 128];   // 32 KB, XOR-swizzled
    int tid = threadIdx.x;
    int w = tid >> 6, lane = tid & 63;
    int row0 = blockIdx.x * 128;

    f32x4 acc[2][8] = {};

    #pragma unroll
    for (int kt = 0; kt < 3; ++kt) {
        const ushort_t* S = (kt == 0) ? feat_bf : (kt == 1) ? ax_bf : ax2_bf;
        __syncthreads();
        {
            int r = tid >> 1, hh = tid & 1;
            int grow = min(row0 + r, NN - 1);
            const char* gsrc = (const char*)(S + grow * DD);
            char* dbase = (char*)As + r * 256;
            int sw = (r & 7) << 4;
            #pragma unroll
            for (int c = 0; c < 8; ++c) {
                int cb = hh * 128 + c * 16;
                *(short8v*)(dbase + (cb ^ sw)) = *(const short8v*)(gsrc + cb);
            }
        }
        {
            int cidx = tid >> 1, hh = tid & 1;
            const char* gsrc = (const char*)(wcT + cidx * 384 + kt * 128);
            char* dbase = (char*)Bs + cidx * 256;
            int sw = (cidx & 7) << 4;
            #pragma unroll
            for (int c = 0; c < 8; ++c) {
                int cb = hh * 128 + c * 16;
                *(short8v*)(dbase + (cb ^ sw)) = *(const short8v*)(gsrc + cb);
            }
        }
        __syncthreads();
        int l15 = lane & 15;
        int r0a = w * 32 + l15;
        int r1a = r0a + 16;
        #pragma unroll
        for (int ks = 0; ks < 4; ++ks) {
            int kb = ks * 64 + ((lane >> 4) << 4);
            short8v a0 = *(const short8v*)((const char*)As + r0a * 256 + (kb ^ ((r0a & 7) << 4)));
            short8v a1 = *(const short8v*)((const char*)As + r1a * 256 + (kb ^ ((r1a & 7) << 4)));
            #pragma unroll
            for (int cf = 0; cf < 8; ++cf) {
                int col = cf * 16 + l15;
                short8v b = *(const short8v*)((const char*)Bs + col * 256 + (kb ^ ((col & 7) << 4)));
                acc[0][cf] = __builtin_amdgcn_mfma_f32_16x16x32_bf16(a0, b, acc[0][cf], 0, 0, 0);
                acc[1][cf] = __builtin_amdgcn_mfma_f32_16x16x32_bf16(a1, b, acc[1][cf], 0, 0, 0);
            }
        }
    }

    int q = lane >> 4, c0 = lane & 15;
    float s1[8], s2[8];
    #pragma unroll
    for (int cf = 0; cf < 8; ++cf) { s1[cf] = 0.f; s2[cf] = 0.f; }

    #pragma unroll
    for (int g = 0; g < 2; ++g) {
        int rbase = row0 + w * 32 + g * 16 + q * 4;
        float sn[4];
        #pragma unroll
        for (int i = 0; i < 4; ++i) sn[i] = (rbase + i < NN) ? snorm[rbase + i] : 0.f;
        #pragma unroll
        for (int cf = 0; cf < 8; ++cf) {
            int col = cf * 16 + c0;
            float bc = bias[col];
            #pragma unroll
            for (int i = 0; i < 4; ++i) {
                int row = rbase + i;
                if (row < NN) {
                    float t = (acc[g][cf][i] + bc) * sn[i];
                    t_out[row * DD + col] = f2b(t);
                    s1[cf] += t; s2[cf] += t * t;
                }
            }
        }
    }
    #pragma unroll
    for (int cf = 0; cf < 8; ++cf) {
        s1[cf] += __shfl_xor(s1[cf], 16); s1[cf] += __shfl_xor(s1[cf], 32);
        s2[cf] += __shfl_xor(s2[cf], 16); s2[cf] += __shfl_xor(s2[cf], 32);
    }
    if (q == 0) {
        int slot = (blockIdx.x & 31) * DD;
        #pragma unroll
        for (int cf = 0; cf < 8; ++cf) {
            atomAdd(&gsums[slot + cf * 16 + c0], s1[cf]);
            atomAdd(&gsq[slot + cf * 16 + c0], s2[cf]);
        }
    }
}

__global__ void bn_finalize(const float* __restrict__ gsums, const float* __restrict__ gsq,
                            const float* __restrict__ gamma,
                            const float* __restrict__ beta,
                            float* __restrict__ scale, float* __restrict__ shift) {
    int d = threadIdx.x;  // 128
    float s1 = 0.f, s2 = 0.f;
    for (int c = 0; c < 32; ++c) { s1 += gsums[c * DD + d]; s2 += gsq[c * DD + d]; }
    float mean = s1 / (float)NN;
    float var  = s2 / (float)NN - mean * mean;
    float sc = gamma[d] * rsqrtf(var + BN_EPS);
    scale[d] = sc;
    shift[d] = beta[d] - mean * sc;
}

// out = feat_bf + relu(t*scale + shift); 8 elems/thread (uint4 in, 2x float4 out)
__global__ void epilogue(const uint4* __restrict__ t4, const uint4* __restrict__ f4,
                         const float* __restrict__ scale, const float* __restrict__ shift,
                         float4* __restrict__ out) {
    int i = blockIdx.x * 256 + threadIdx.x;   // 3125*256 = 800000 = NN*DD/8 exact
    int d0 = (i << 3) & 127;
    uint4 tv = t4[i];
    uint4 fv = f4[i];
    float4 o0, o1;
    o0.x = b2f((ushort_t)(fv.x))       + fmaxf(b2f((ushort_t)(tv.x))       * scale[d0+0] + shift[d0+0], 0.f);
    o0.y = b2f((ushort_t)(fv.x >> 16)) + fmaxf(b2f((ushort_t)(tv.x >> 16)) * scale[d0+1] + shift[d0+1], 0.f);
    o0.z = b2f((ushort_t)(fv.y))       + fmaxf(b2f((ushort_t)(tv.y))       * scale[d0+2] + shift[d0+2], 0.f);
    o0.w = b2f((ushort_t)(fv.y >> 16)) + fmaxf(b2f((ushort_t)(tv.y >> 16)) * scale[d0+3] + shift[d0+3], 0.f);
    o1.x = b2f((ushort_t)(fv.z))       + fmaxf(b2f((ushort_t)(tv.z))       * scale[d0+4] + shift[d0+4], 0.f);
    o1.y = b2f((ushort_t)(fv.z >> 16)) + fmaxf(b2f((ushort_t)(tv.z >> 16)) * scale[d0+5] + shift[d0+5], 0.f);
    o1.z = b2f((ushort_t)(fv.w))       + fmaxf(b2f((ushort_t)(tv.w))       * scale[d0+6] + shift[d0+6], 0.f);
    o1.w = b2f((ushort_t)(fv.w >> 16)) + fmaxf(b2f((ushort_t)(tv.w >> 16)) * scale[d0+7] + shift[d0+7], 0.f);
    out[2 * i]     = o0;
    out[2 * i + 1] = o1;
}

extern "C" void kernel_launch(void* const* d_in, const int* in_sizes, int n_in,
                              void* d_out, int out_size, void* d_ws, size_t ws_size,
                              hipStream_t stream) {
    const float* feat  = (const float*)d_in[0];
    const float* snorm = (const float*)d_in[1];
    const float* W1    = (const float*)d_in[2];
    const float* W2    = (const float*)d_in[3];
    const float* W3    = (const float*)d_in[4];
    const float* bias  = (const float*)d_in[5];
    const float* gamma = (const float*)d_in[6];
    const float* beta  = (const float*)d_in[7];
    const int* esrc = (const int*)d_in[8];
    const int* edst = (const int*)d_in[9];
    float* out = (float*)d_out;

    char* ws = (char*)d_ws;
    ushort_t* t_bf    = (ushort_t*)(ws);                 // 12,800,000 (gemm output)
    ushort_t* rank16  = (ushort_t*)(ws);                 //  1,600,000 ALIAS of t_bf
                                                         //  (rank16 dead before gemm_bn)
    ushort_t* feat_bf = (ushort_t*)(ws + 12800000);      // 12,800,000
    ushort_t* ax_bf   = (ushort_t*)(ws + 25600000);      // 12,800,000
    int*      cnt_blk = (int*)     (ws + 25600000);      // 12,500,000 ALIAS of ax_bf
                                                         //  (cnt_blk dead before gather#1 writes ax_bf)
    ushort_t* ax2_bf  = (ushort_t*)(ws + 38400000);      // 12,800,000
    int2*     csr     = (int2*)    (ws + 51200000);      //  6,400,000 (src, norm bits)
    float*    norm    = (float*)   (ws + 57600000);      //    200,000
    int*      deg     = (int*)     (ws + 57800000);      //    200,000
    float*    gsums   = (float*)   (ws + 58000000);      //     16,384
    float*    gsq     = (float*)   (ws + 58016384);      //     16,384
    int*      off     = (int*)     (ws + 58032768);      //    200,064
    int*      part    = (int*)     (ws + 58232832);      //        512
    float*    scale   = (float*)   (ws + 58233856);      //        512
    float*    shift   = (float*)   (ws + 58234368);      //        512
    ushort_t* wcT     = (ushort_t*)(ws + 58234880);      //     98,304 (end 58,333,184)

    lds_count <<<NB, BT, 0, stream>>>(edst, cnt_blk, rank16, feat, feat_bf,
                                      (float4*)(ws + 58000000), part);
    col_scan  <<<98, 256, 0, stream>>>(cnt_blk, (int2*)deg, norm, part);
    scan_final<<<SCAN_G + 96, 512, 0, stream>>>(deg, part, off, W1, W2, W3, wcT);
    fill2     <<<3125, 256, 0, stream>>>(esrc, edst, rank16, cnt_blk, off, norm, csr);

    gather_bf<<<3125, 256, 0, stream>>>(feat_bf, norm, off, csr, ax_bf);
    gather_bf<<<3125, 256, 0, stream>>>(ax_bf,   norm, off, csr, ax2_bf);

    gemm_bn<<<391, 256, 0, stream>>>(feat_bf, ax_bf, ax2_bf, wcT, bias, snorm,
                                     t_bf, gsums, gsq);
    bn_finalize<<<1, 128, 0, stream>>>(gsums, gsq, gamma, beta, scale, shift);
    epilogue   <<<3125, 256, 0, stream>>>((const uint4*)t_bf, (const uint4*)feat_bf,
                                          scale, shift, (float4*)out);
}

// Round 22
// 154.660 us; speedup vs baseline: 1.5048x; 1.5048x over previous
//
#include <hip/hip_runtime.h>
#include <hip/hip_bf16.h>

#define NN 50000
#define NE 800000
#define DD 128
#define BN_EPS 1e-5f
#define SCAN_G 98     // 98*512 = 50176 >= NN
#define NB 125        // edge chunks (blocks) in lds_count
#define BT 640        // lds_count block threads (10 waves)
#define CHUNK 6400    // NB*CHUNK = NE; 6400 = 10*640 (exact)
#define NWRD 25000    // packed u16x2 counters: 2 dst per u32 word

typedef unsigned short ushort_t;
typedef unsigned int uint_t;
typedef __attribute__((ext_vector_type(8))) short short8v;   // 8 x bf16 (4 VGPR)
typedef __attribute__((ext_vector_type(4))) float f32x4;

__device__ __forceinline__ float b2f(ushort_t u) {
    union { uint_t i; float f; } v; v.i = ((uint_t)u) << 16; return v.f;
}
__device__ __forceinline__ ushort_t f2b(float f) {
    uint_t u = __float_as_uint(f);
    u += 0x7FFFu + ((u >> 16) & 1u);   // RNE
    return (ushort_t)(u >> 16);
}
__device__ __forceinline__ void atomAdd(float* p, float v) { unsafeAtomicAdd(p, v); }

// ---------- pass A: per-block LDS histogram + local rank + feat->bf16 ----------
// h[w] packs counts for dst=2w (lo16) and dst=2w+1 (hi16). Per-block count
// <= 6400 so no overflow / no cross-half carry. LDS atomic returns local rank.
__global__ __launch_bounds__(BT) void lds_count(const int* __restrict__ dst,
                                                int* __restrict__ cnt_block,
                                                ushort_t* __restrict__ rank16,
                                                const float* __restrict__ feat,
                                                ushort_t* __restrict__ feat_bf,
                                                float4* __restrict__ gz) {
    __shared__ uint_t h[NWRD];     // 100 KB
    int b = blockIdx.x, t = threadIdx.x;
    for (int i = t; i < NWRD; i += BT) h[i] = 0u;
    // feat conversion, grid-strided: 1.6M float4 / 80000 threads = 20 exact
    {
        const float4* fp = reinterpret_cast<const float4*>(feat);
        ushort4* op = reinterpret_cast<ushort4*>(feat_bf);
        for (int i = b * BT + t; i < 1600000; i += NB * BT) {
            float4 v = fp[i];
            ushort4 o = { f2b(v.x), f2b(v.y), f2b(v.z), f2b(v.w) };
            op[i] = o;
        }
    }
    if (b == 0) {
        float4 z = make_float4(0.f, 0.f, 0.f, 0.f);
        for (int i = t; i < 2048; i += BT) gz[i] = z;   // gsums+gsq = 32 KB
    }
    __syncthreads();
    int e0 = b * CHUNK;
    #pragma unroll
    for (int k = 0; k < 10; ++k) {         // 10*640 = 6400 exact
        int e = e0 + k * BT + t;
        int d = dst[e];
        int sh = (d & 1) << 4;
        uint_t old = atomicAdd(&h[d >> 1], 1u << sh);
        rank16[e] = (ushort_t)((old >> sh) & 0xFFFFu);
    }
    __syncthreads();
    for (int i = t; i < NWRD; i += BT) cnt_block[b * NWRD + i] = (int)h[i];
}

// ---------- pass B: per-word exclusive scan over blocks (in place) ----------
// Also emits deg, norm, and per-block partial sums (one PLAIN STORE per block
// -- w>>8 == blockIdx.x, so each part slot is block-private; no atomics).
__global__ __launch_bounds__(256) void col_scan(int* __restrict__ cnt_block,
                                                int2* __restrict__ deg2,
                                                float* __restrict__ norm,
                                                int* __restrict__ part) {
    __shared__ int wsum[4];
    int t = threadIdx.x;
    int w = blockIdx.x * 256 + t;   // 98*256 = 25088 >= NWRD
    int mysum = 0;
    if (w < NWRD) {
        uint_t run = 0;
        #pragma unroll 5
        for (int b = 0; b < NB; ++b) {
            uint_t v = (uint_t)cnt_block[b * NWRD + w];
            cnt_block[b * NWRD + w] = (int)run;
            run += v;
        }
        int d0 = (int)(run & 0xFFFFu), d1 = (int)(run >> 16);
        deg2[w] = make_int2(d0, d1);
        norm[2 * w]     = rsqrtf((float)max(d0, 1));   // 2w   <= 49998 < NN
        norm[2 * w + 1] = rsqrtf((float)max(d1, 1));   // 2w+1 <= 49999 < NN
        mysum = d0 + d1;
    }
    #pragma unroll
    for (int s = 1; s < 64; s <<= 1) mysum += __shfl_xor(mysum, s);
    if ((t & 63) == 0) wsum[t >> 6] = mysum;
    __syncthreads();
    if (t == 0) part[blockIdx.x] = wsum[0] + wsum[1] + wsum[2] + wsum[3];
}

// off-scan (blocks < SCAN_G): block-local exclusive scan + in-block base.
// blocks >= SCAN_G: build WcT (128x384 bf16).
__global__ __launch_bounds__(512) void scan_final(const int* __restrict__ deg,
                                                  const int* __restrict__ part,
                                                  int* __restrict__ off,
                                                  const float* __restrict__ W1,
                                                  const float* __restrict__ W2,
                                                  const float* __restrict__ W3,
                                                  ushort_t* __restrict__ wcT) {
    if (blockIdx.x >= SCAN_G) {
        int i = (blockIdx.x - SCAN_G) * 512 + threadIdx.x;   // 96*512 = 49152
        int d = i / 384, k = i % 384;
        float v;
        if (k < 128)      v = W1[k * DD + d] - W3[k * DD + d];
        else if (k < 256) v = -W2[(k - 128) * DD + d];
        else              v = 2.0f * W3[(k - 256) * DD + d];
        wcT[i] = f2b(v);
        return;
    }
    __shared__ int wsum[8];
    __shared__ int sbase;
    int t = threadIdx.x;
    int lane = t & 63, wv = t >> 6;

    int p = (t < blockIdx.x && t < SCAN_G) ? part[t] : 0;
    #pragma unroll
    for (int s = 1; s < 64; s <<= 1) p += __shfl_xor(p, s);
    if (lane == 0) wsum[wv] = p;
    __syncthreads();
    if (t == 0) {
        int b = 0;
        #pragma unroll
        for (int k = 0; k < 8; ++k) b += wsum[k];
        sbase = b;
    }
    __syncthreads();

    int i = blockIdx.x * 512 + t;
    int v = (i < NN) ? deg[i] : 0;
    int incl = v;
    #pragma unroll
    for (int s = 1; s < 64; s <<= 1) {
        int u = __shfl_up(incl, s);
        if (lane >= s) incl += u;
    }
    __syncthreads();
    if (lane == 63) wsum[wv] = incl;
    __syncthreads();
    int woff = 0;
    for (int k = 0; k < wv; ++k) woff += wsum[k];
    int excl = sbase + woff + incl - v;
    if (i < NN) off[i] = excl;
    if (blockIdx.x == 0 && t == 0) off[NN] = NE;
}

// ---------- pass C: atomic-free CSR fill ----------
// p = off[dst] + prefix[block][dst] + rank16[e]
__global__ void fill2(const int* __restrict__ src, const int* __restrict__ dst,
                      const ushort_t* __restrict__ rank16,
                      const int* __restrict__ cnt_block,   // now prefix
                      const int* __restrict__ off,
                      const float* __restrict__ norm, int2* __restrict__ csr) {
    int e = blockIdx.x * 256 + threadIdx.x;
    if (e >= NE) return;
    int b = e / CHUNK;
    int s = src[e], d = dst[e];
    int sh = (d & 1) << 4;
    uint_t pref = ((uint_t)cnt_block[b * NWRD + (d >> 1)] >> sh) & 0xFFFFu;
    int p = off[d] + (int)pref + (int)rank16[e];
    csr[p] = make_int2(s, __float_as_int(norm[s]));
}

// ---------- message passing (bf16 in, bf16 out) ----------
// QUARTER-WAVE (16 lanes) per NODE; lane covers 8 cols (uint4 = 16B).
__global__ __launch_bounds__(256) void gather_bf(const ushort_t* __restrict__ x,
                                                 const float* __restrict__ norm,
                                                 const int* __restrict__ off,
                                                 const int2* __restrict__ csr,
                                                 ushort_t* __restrict__ out) {
    int g = (blockIdx.x << 4) | (threadIdx.x >> 4);   // node id; 3125*16 = 50000
    int l4 = threadIdx.x & 15;
    int jb = off[g], je = off[g + 1];
    const uint4* xp = reinterpret_cast<const uint4*>(x);   // row = 16 x uint4
    float a0 = 0.f, a1 = 0.f, a2 = 0.f, a3 = 0.f;
    float a4 = 0.f, a5 = 0.f, a6 = 0.f, a7 = 0.f;

#define ACC(cc, vv)                                                  \
    {                                                                \
        float n_ = __int_as_float(cc.y);                             \
        a0 = fmaf(n_, b2f((ushort_t)(vv.x)), a0);                    \
        a1 = fmaf(n_, b2f((ushort_t)(vv.x >> 16)), a1);              \
        a2 = fmaf(n_, b2f((ushort_t)(vv.y)), a2);                    \
        a3 = fmaf(n_, b2f((ushort_t)(vv.y >> 16)), a3);              \
        a4 = fmaf(n_, b2f((ushort_t)(vv.z)), a4);                    \
        a5 = fmaf(n_, b2f((ushort_t)(vv.z >> 16)), a5);              \
        a6 = fmaf(n_, b2f((ushort_t)(vv.w)), a6);                    \
        a7 = fmaf(n_, b2f((ushort_t)(vv.w >> 16)), a7);              \
    }

    int j = jb;
    for (; j + 4 <= je; j += 4) {
        int2 c0 = csr[j + 0];
        int2 c1 = csr[j + 1];
        int2 c2 = csr[j + 2];
        int2 c3 = csr[j + 3];
        uint4 v0 = xp[(size_t)c0.x * 16 + l4];
        uint4 v1 = xp[(size_t)c1.x * 16 + l4];
        uint4 v2 = xp[(size_t)c2.x * 16 + l4];
        uint4 v3 = xp[(size_t)c3.x * 16 + l4];
        ACC(c0, v0); ACC(c1, v1); ACC(c2, v2); ACC(c3, v3);
    }
    for (; j < je; ++j) {
        int2 c = csr[j];
        uint4 v = xp[(size_t)c.x * 16 + l4];
        ACC(c, v);
    }
#undef ACC

    float nd = norm[g];
    uint4 o;
    o.x = (uint_t)f2b(nd * a0) | ((uint_t)f2b(nd * a1) << 16);
    o.y = (uint_t)f2b(nd * a2) | ((uint_t)f2b(nd * a3) << 16);
    o.z = (uint_t)f2b(nd * a4) | ((uint_t)f2b(nd * a5) << 16);
    o.w = (uint_t)f2b(nd * a6) | ((uint_t)f2b(nd * a7) << 16);
    reinterpret_cast<uint4*>(out)[(size_t)g * 16 + l4] = o;
}

// ---------- MFMA GEMM + BN partials ----------
__global__ __launch_bounds__(256) void gemm_bn(
    const ushort_t* __restrict__ feat_bf, const ushort_t* __restrict__ ax_bf,
    const ushort_t* __restrict__ ax2_bf, const ushort_t* __restrict__ wcT,
    const float* __restrict__ bias, const float* __restrict__ snorm,
    ushort_t* __restrict__ t_out, float* __restrict__ gsums, float* __restrict__ gsq)
{
    __shared__ ushort_t As[128 * 128];   // 32 KB, XOR-swizzled
    __shared__ ushort_t Bs[128 * 128];   // 32 KB, XOR-swizzled
    int tid = threadIdx.x;
    int w = tid >> 6, lane = tid & 63;
    int row0 = blockIdx.x * 128;

    f32x4 acc[2][8] = {};

    #pragma unroll
    for (int kt = 0; kt < 3; ++kt) {
        const ushort_t* S = (kt == 0) ? feat_bf : (kt == 1) ? ax_bf : ax2_bf;
        __syncthreads();
        {
            int r = tid >> 1, hh = tid & 1;
            int grow = min(row0 + r, NN - 1);
            const char* gsrc = (const char*)(S + grow * DD);
            char* dbase = (char*)As + r * 256;
            int sw = (r & 7) << 4;
            #pragma unroll
            for (int c = 0; c < 8; ++c) {
                int cb = hh * 128 + c * 16;
                *(short8v*)(dbase + (cb ^ sw)) = *(const short8v*)(gsrc + cb);
            }
        }
        {
            int cidx = tid >> 1, hh = tid & 1;
            const char* gsrc = (const char*)(wcT + cidx * 384 + kt * 128);
            char* dbase = (char*)Bs + cidx * 256;
            int sw = (cidx & 7) << 4;
            #pragma unroll
            for (int c = 0; c < 8; ++c) {
                int cb = hh * 128 + c * 16;
                *(short8v*)(dbase + (cb ^ sw)) = *(const short8v*)(gsrc + cb);
            }
        }
        __syncthreads();
        int l15 = lane & 15;
        int r0a = w * 32 + l15;
        int r1a = r0a + 16;
        #pragma unroll
        for (int ks = 0; ks < 4; ++ks) {
            int kb = ks * 64 + ((lane >> 4) << 4);
            short8v a0 = *(const short8v*)((const char*)As + r0a * 256 + (kb ^ ((r0a & 7) << 4)));
            short8v a1 = *(const short8v*)((const char*)As + r1a * 256 + (kb ^ ((r1a & 7) << 4)));
            #pragma unroll
            for (int cf = 0; cf < 8; ++cf) {
                int col = cf * 16 + l15;
                short8v b = *(const short8v*)((const char*)Bs + col * 256 + (kb ^ ((col & 7) << 4)));
                acc[0][cf] = __builtin_amdgcn_mfma_f32_16x16x32_bf16(a0, b, acc[0][cf], 0, 0, 0);
                acc[1][cf] = __builtin_amdgcn_mfma_f32_16x16x32_bf16(a1, b, acc[1][cf], 0, 0, 0);
            }
        }
    }

    int q = lane >> 4, c0 = lane & 15;
    float s1[8], s2[8];
    #pragma unroll
    for (int cf = 0; cf < 8; ++cf) { s1[cf] = 0.f; s2[cf] = 0.f; }

    #pragma unroll
    for (int g = 0; g < 2; ++g) {
        int rbase = row0 + w * 32 + g * 16 + q * 4;
        float sn[4];
        #pragma unroll
        for (int i = 0; i < 4; ++i) sn[i] = (rbase + i < NN) ? snorm[rbase + i] : 0.f;
        #pragma unroll
        for (int cf = 0; cf < 8; ++cf) {
            int col = cf * 16 + c0;
            float bc = bias[col];
            #pragma unroll
            for (int i = 0; i < 4; ++i) {
                int row = rbase + i;
                if (row < NN) {
                    float t = (acc[g][cf][i] + bc) * sn[i];
                    t_out[row * DD + col] = f2b(t);
                    s1[cf] += t; s2[cf] += t * t;
                }
            }
        }
    }
    #pragma unroll
    for (int cf = 0; cf < 8; ++cf) {
        s1[cf] += __shfl_xor(s1[cf], 16); s1[cf] += __shfl_xor(s1[cf], 32);
        s2[cf] += __shfl_xor(s2[cf], 16); s2[cf] += __shfl_xor(s2[cf], 32);
    }
    if (q == 0) {
        int slot = (blockIdx.x & 31) * DD;
        #pragma unroll
        for (int cf = 0; cf < 8; ++cf) {
            atomAdd(&gsums[slot + cf * 16 + c0], s1[cf]);
            atomAdd(&gsq[slot + cf * 16 + c0], s2[cf]);
        }
    }
}

__global__ void bn_finalize(const float* __restrict__ gsums, const float* __restrict__ gsq,
                            const float* __restrict__ gamma,
                            const float* __restrict__ beta,
                            float* __restrict__ scale, float* __restrict__ shift) {
    int d = threadIdx.x;  // 128
    float s1 = 0.f, s2 = 0.f;
    for (int c = 0; c < 32; ++c) { s1 += gsums[c * DD + d]; s2 += gsq[c * DD + d]; }
    float mean = s1 / (float)NN;
    float var  = s2 / (float)NN - mean * mean;
    float sc = gamma[d] * rsqrtf(var + BN_EPS);
    scale[d] = sc;
    shift[d] = beta[d] - mean * sc;
}

// out = feat_bf + relu(t*scale + shift); 8 elems/thread (uint4 in, 2x float4 out)
__global__ void epilogue(const uint4* __restrict__ t4, const uint4* __restrict__ f4,
                         const float* __restrict__ scale, const float* __restrict__ shift,
                         float4* __restrict__ out) {
    int i = blockIdx.x * 256 + threadIdx.x;   // 3125*256 = 800000 = NN*DD/8 exact
    int d0 = (i << 3) & 127;
    uint4 tv = t4[i];
    uint4 fv = f4[i];
    float4 o0, o1;
    o0.x = b2f((ushort_t)(fv.x))       + fmaxf(b2f((ushort_t)(tv.x))       * scale[d0+0] + shift[d0+0], 0.f);
    o0.y = b2f((ushort_t)(fv.x >> 16)) + fmaxf(b2f((ushort_t)(tv.x >> 16)) * scale[d0+1] + shift[d0+1], 0.f);
    o0.z = b2f((ushort_t)(fv.y))       + fmaxf(b2f((ushort_t)(tv.y))       * scale[d0+2] + shift[d0+2], 0.f);
    o0.w = b2f((ushort_t)(fv.y >> 16)) + fmaxf(b2f((ushort_t)(tv.y >> 16)) * scale[d0+3] + shift[d0+3], 0.f);
    o1.x = b2f((ushort_t)(fv.z))       + fmaxf(b2f((ushort_t)(tv.z))       * scale[d0+4] + shift[d0+4], 0.f);
    o1.y = b2f((ushort_t)(fv.z >> 16)) + fmaxf(b2f((ushort_t)(tv.z >> 16)) * scale[d0+5] + shift[d0+5], 0.f);
    o1.z = b2f((ushort_t)(fv.w))       + fmaxf(b2f((ushort_t)(tv.w))       * scale[d0+6] + shift[d0+6], 0.f);
    o1.w = b2f((ushort_t)(fv.w >> 16)) + fmaxf(b2f((ushort_t)(tv.w >> 16)) * scale[d0+7] + shift[d0+7], 0.f);
    out[2 * i]     = o0;
    out[2 * i + 1] = o1;
}

extern "C" void kernel_launch(void* const* d_in, const int* in_sizes, int n_in,
                              void* d_out, int out_size, void* d_ws, size_t ws_size,
                              hipStream_t stream) {
    const float* feat  = (const float*)d_in[0];
    const float* snorm = (const float*)d_in[1];
    const float* W1    = (const float*)d_in[2];
    const float* W2    = (const float*)d_in[3];
    const float* W3    = (const float*)d_in[4];
    const float* bias  = (const float*)d_in[5];
    const float* gamma = (const float*)d_in[6];
    const float* beta  = (const float*)d_in[7];
    const int* esrc = (const int*)d_in[8];
    const int* edst = (const int*)d_in[9];
    float* out = (float*)d_out;

    char* ws = (char*)d_ws;
    ushort_t* t_bf    = (ushort_t*)(ws);                 // 12,800,000 (gemm output)
    ushort_t* rank16  = (ushort_t*)(ws);                 //  1,600,000 ALIAS of t_bf
                                                         //  (rank16 dead before gemm_bn)
    ushort_t* feat_bf = (ushort_t*)(ws + 12800000);      // 12,800,000
    ushort_t* ax_bf   = (ushort_t*)(ws + 25600000);      // 12,800,000
    int*      cnt_blk = (int*)     (ws + 25600000);      // 12,500,000 ALIAS of ax_bf
                                                         //  (cnt_blk dead before gather#1 writes ax_bf)
    ushort_t* ax2_bf  = (ushort_t*)(ws + 38400000);      // 12,800,000
    int2*     csr     = (int2*)    (ws + 51200000);      //  6,400,000 (src, norm bits)
    float*    norm    = (float*)   (ws + 57600000);      //    200,000
    int*      deg     = (int*)     (ws + 57800000);      //    200,000
    float*    gsums   = (float*)   (ws + 58000000);      //     16,384
    float*    gsq     = (float*)   (ws + 58016384);      //     16,384
    int*      off     = (int*)     (ws + 58032768);      //    200,064
    int*      part    = (int*)     (ws + 58232832);      //        512
    float*    scale   = (float*)   (ws + 58233856);      //        512
    float*    shift   = (float*)   (ws + 58234368);      //        512
    ushort_t* wcT     = (ushort_t*)(ws + 58234880);      //     98,304 (end 58,333,184)

    lds_count <<<NB, BT, 0, stream>>>(edst, cnt_blk, rank16, feat, feat_bf,
                                      (float4*)(ws + 58000000));
    col_scan  <<<98, 256, 0, stream>>>(cnt_blk, (int2*)deg, norm, part);
    scan_final<<<SCAN_G + 96, 512, 0, stream>>>(deg, part, off, W1, W2, W3, wcT);
    fill2     <<<3125, 256, 0, stream>>>(esrc, edst, rank16, cnt_blk, off, norm, csr);

    gather_bf<<<3125, 256, 0, stream>>>(feat_bf, norm, off, csr, ax_bf);
    gather_bf<<<3125, 256, 0, stream>>>(ax_bf,   norm, off, csr, ax2_bf);

    gemm_bn<<<391, 256, 0, stream>>>(feat_bf, ax_bf, ax2_bf, wcT, bias, snorm,
                                     t_bf, gsums, gsq);
    bn_finalize<<<1, 128, 0, stream>>>(gsums, gsq, gamma, beta, scale, shift);
    epilogue   <<<3125, 256, 0, stream>>>((const uint4*)t_bf, (const uint4*)feat_bf,
                                          scale, shift, (float4*)out);
}